// Round 1
// baseline (196.993 us; speedup 1.0000x reference)
//
#include <hip/hip_runtime.h>
#include <stdint.h>

#define EPSF 1e-6f

typedef unsigned short u16;
typedef __attribute__((ext_vector_type(8))) u16 u16x8;
typedef __attribute__((ext_vector_type(8))) __bf16 bf16x8;
typedef __attribute__((ext_vector_type(4))) float f32x4;

static constexpr int NBI = 128, NBT = 128, KI = 36, LC = 50, DD = 1024;
static constexpr int NEL = KI * LC;   // 1800
static constexpr int GM  = NBI * KI;  // 4608 rows of A  (i*36+k)
static constexpr int GN  = NBT * LC;  // 6400 rows of B^T (t*50+l)

static __device__ __forceinline__ u16 f2bf(float f) {  // round-to-nearest-even
  uint32_t u = __float_as_uint(f);
  u += 0x7fffu + ((u >> 16) & 1u);
  return (u16)(u >> 16);
}
static __device__ __forceinline__ float bf2f(u16 h) {
  return __uint_as_float((uint32_t)h << 16);
}

typedef __attribute__((address_space(1))) void gv_t;
typedef __attribute__((address_space(3))) void lv_t;
// async global->LDS, 16B per lane; LDS dest must be the wave-uniform base.
static __device__ __forceinline__ void gload16(const void* g, void* l) {
  __builtin_amdgcn_global_load_lds((const gv_t*)g, (lv_t*)l, 16, 0, 0);
}

// ---------------- kernel 0: add EPS, L2-normalize rows, cast to bf16 ----------------
__global__ __launch_bounds__(256) void hcam_normcast(
    const float* __restrict__ imgs, const float* __restrict__ caps,
    u16* __restrict__ A, u16* __restrict__ B) {
  int r = blockIdx.x;
  const float* src; u16* dst;
  if (r < GM) { src = imgs + (size_t)r * DD;        dst = A + (size_t)r * DD; }
  else        { src = caps + (size_t)(r - GM) * DD; dst = B + (size_t)(r - GM) * DD; }
  int tid = threadIdx.x;
  float4 v = *(const float4*)(src + tid * 4);   // 256 thr * 4 = 1024
  v.x += EPSF; v.y += EPSF; v.z += EPSF; v.w += EPSF;
  float ss = v.x * v.x + v.y * v.y + v.z * v.z + v.w * v.w;
  #pragma unroll
  for (int m = 32; m; m >>= 1) ss += __shfl_xor(ss, m);
  __shared__ float wsum[4];
  if ((tid & 63) == 0) wsum[tid >> 6] = ss;
  __syncthreads();
  float inv = 1.0f / sqrtf(wsum[0] + wsum[1] + wsum[2] + wsum[3]);
  ushort4 o = make_ushort4(f2bf(v.x * inv), f2bf(v.y * inv), f2bf(v.z * inv), f2bf(v.w * inv));
  *(ushort4*)(dst + tid * 4) = o;
}

// ---------------- kernel 1: C = A * B^T   (m97-style 128x128 tile, BK=64) ----------------
__global__ __launch_bounds__(256) void hcam_gemm(
    const u16* __restrict__ A, const u16* __restrict__ B, float* __restrict__ C) {
  __shared__ u16 a_t[128 * 64];   // 16 KB, row-major [row][k]
  __shared__ u16 b_t[128 * 64];   // 16 KB, row-major [col][k] (B^T)
  const int b   = blockIdx.x;
  const int bm  = b % (GM / 128);        // 36 M-tiles
  const int bn  = b / (GM / 128);        // 50 N-tiles
  const int tid = threadIdx.x;
  const int w = tid >> 6, lane = tid & 63;
  const int wr = w >> 1, wc = w & 1;     // 2x2 waves, 64x64 out each
  const int srow = lane >> 3;            // staging: 8 rows / wave-issue
  const int scol = (lane & 7) * 8;       // 8 bf16 = 16B per lane
  const size_t arow0 = (size_t)(bm * 128) * DD;
  const size_t brow0 = (size_t)(bn * 128) * DD;

  f32x4 zz = {0.f, 0.f, 0.f, 0.f};
  f32x4 acc[4][4];
  #pragma unroll
  for (int i = 0; i < 4; ++i)
    #pragma unroll
    for (int j = 0; j < 4; ++j) acc[i][j] = zz;

  const int fr = lane & 15, kg = (lane >> 4) * 8;  // frag row/col + k-group

  for (int kt = 0; kt < DD / 64; ++kt) {
    const int kb = kt * 64;
    #pragma unroll
    for (int j = 0; j < 4; ++j) {
      const int jj = w * 4 + j;          // 16 x 1KB issues cover each 16KB tile
      const int rr = jj * 8 + srow;      // tile row 0..127
      gload16(A + arow0 + (size_t)rr * DD + kb + scol, &a_t[jj * 512]);
      gload16(B + brow0 + (size_t)rr * DD + kb + scol, &b_t[jj * 512]);
    }
    __syncthreads();   // drains vmcnt before use
    #pragma unroll
    for (int kk = 0; kk < 64; kk += 32) {
      bf16x8 af[4], bfv[4];
      #pragma unroll
      for (int mi = 0; mi < 4; ++mi) {
        const int row = wr * 64 + mi * 16 + fr;
        af[mi] = __builtin_bit_cast(bf16x8, *(const u16x8*)&a_t[row * 64 + kk + kg]);
      }
      #pragma unroll
      for (int ni = 0; ni < 4; ++ni) {
        const int row = wc * 64 + ni * 16 + fr;
        bfv[ni] = __builtin_bit_cast(bf16x8, *(const u16x8*)&b_t[row * 64 + kk + kg]);
      }
      #pragma unroll
      for (int mi = 0; mi < 4; ++mi)
        #pragma unroll
        for (int ni = 0; ni < 4; ++ni)
          acc[mi][ni] = __builtin_amdgcn_mfma_f32_16x16x32_bf16(af[mi], bfv[ni], acc[mi][ni], 0, 0, 0);
    }
    __syncthreads();
  }
  // C/D layout (m89-verified): col = lane&15, row = (lane>>4)*4 + j
  const int fc = lane & 15, fq = (lane >> 4) * 4;
  #pragma unroll
  for (int mi = 0; mi < 4; ++mi) {
    #pragma unroll
    for (int ni = 0; ni < 4; ++ni) {
      const int col  = bn * 128 + wc * 64 + ni * 16 + fc;
      const int row0 = bm * 128 + wr * 64 + mi * 16 + fq;
      #pragma unroll
      for (int j = 0; j < 4; ++j)
        C[(size_t)(row0 + j) * GN + col] = acc[mi][ni][j];
    }
  }
}

// ---------------- block reduction of two floats (256 threads) ----------------
static __device__ __forceinline__ void bred2(float& a, float& b2, int tid, float* red) {
  #pragma unroll
  for (int m = 32; m; m >>= 1) { a += __shfl_xor(a, m); b2 += __shfl_xor(b2, m); }
  __syncthreads();                              // protect red reuse across iters
  if ((tid & 63) == 0) { red[(tid >> 6) * 2] = a; red[(tid >> 6) * 2 + 1] = b2; }
  __syncthreads();
  a  = red[0] + red[2] + red[4] + red[6];
  b2 = red[1] + red[3] + red[5] + red[7];
}

// ---------------- sparsemax over 1800 register-resident values + weighted sum ----------------
// Michelot projection: tau <- (sum_{z>tau} - 1)/cnt, set shrinks monotonically.
// Masked entries are exact 0 and PARTICIPATE (n=1800); pad slots p>=1800 excluded.
static __device__ __forceinline__ void sparsemax_out(float vals[8], int tid, float* red, float* outp) {
  float s = 0.f, d = 0.f;
  #pragma unroll
  for (int r = 0; r < 8; ++r) { int p = tid + (r << 8); if (p < NEL) s += vals[r]; }
  bred2(s, d, tid, red);
  float tau  = (s - 1.0f) * (1.0f / NEL);
  float prev = (float)NEL;
  for (int it = 0; it < 64; ++it) {
    float ss = 0.f, cc = 0.f;
    #pragma unroll
    for (int r = 0; r < 8; ++r) {
      int p = tid + (r << 8);
      if (p < NEL && vals[r] > tau) { ss += vals[r]; cc += 1.0f; }
    }
    bred2(ss, cc, tid, red);
    if (cc == prev || cc < 1.0f) break;   // support stable -> converged
    float tn = (ss - 1.0f) / cc;
    prev = cc;
    if (tn <= tau) break;                 // rounding guard (tau must increase)
    tau = tn;
  }
  float o = 0.f; d = 0.f;
  #pragma unroll
  for (int r = 0; r < 8; ++r) {
    float v = vals[r], a2 = v - tau;
    if (a2 > 0.f) o += v * a2;            // masked v==0 contributes 0
  }
  bred2(o, d, tid, red);
  if (tid == 0) *outp = o;
}

// ---------------- kernel 2: gather fg block, mask, sparsemax, output ----------------
__global__ __launch_bounds__(256) void hcam_spmax(
    const float* __restrict__ C, const int* __restrict__ ilen, const int* __restrict__ clen,
    float* __restrict__ out) {
  const int b = blockIdx.x;
  const int i = b >> 7, t = b & 127;
  const int tid = threadIdx.x;
  const int il = ilen[i], cl = clen[t];
  const float* base = C + (size_t)i * KI * GN + t * LC;
  float vals[8];
  #pragma unroll
  for (int r = 0; r < 8; ++r) {
    int p = tid + (r << 8);
    float v = 0.f;
    if (p < NEL) {
      int k = p / LC, l = p - k * LC;
      if (k < il && l < cl) v = base[(size_t)k * GN + l];
    }
    vals[r] = v;
  }
  __shared__ float red[8];
  sparsemax_out(vals, tid, red, &out[b]);
}

// ---------------- fallback tier 2: fused dots from normalized bf16 (ws >= 22.6MB) ----------------
__global__ __launch_bounds__(256) void hcam_fused_bf(
    const u16* __restrict__ A, const u16* __restrict__ B,
    const int* __restrict__ ilen, const int* __restrict__ clen, float* __restrict__ out) {
  const int b = blockIdx.x;
  const int i = b >> 7, t = b & 127;
  const int tid = threadIdx.x;
  const int il = ilen[i], cl = clen[t];
  float vals[8];
  #pragma unroll
  for (int r = 0; r < 8; ++r) {
    int p = tid + (r << 8);
    float v = 0.f;
    if (p < NEL) {
      int k = p / LC, l = p - k * LC;
      if (k < il && l < cl) {
        const u16* ar = A + (size_t)(i * KI + k) * DD;
        const u16* br = B + (size_t)(t * LC + l) * DD;
        float s = 0.f;
        for (int dd = 0; dd < DD; dd += 8) {
          u16x8 av = *(const u16x8*)(ar + dd);
          u16x8 bv = *(const u16x8*)(br + dd);
          #pragma unroll
          for (int q = 0; q < 8; ++q) s += bf2f(av[q]) * bf2f(bv[q]);
        }
        v = s;
      }
    }
    vals[r] = v;
  }
  __shared__ float red[8];
  sparsemax_out(vals, tid, red, &out[b]);
}

// ---------------- fallback tier 3: fully fused, norms recomputed (no ws needed) ----------------
__global__ __launch_bounds__(256) void hcam_fused_raw(
    const float* __restrict__ imgs, const float* __restrict__ caps,
    const int* __restrict__ ilen, const int* __restrict__ clen, float* __restrict__ out) {
  const int b = blockIdx.x;
  const int i = b >> 7, t = b & 127;
  const int tid = threadIdx.x;
  const int w = tid >> 6, lane = tid & 63;
  __shared__ float inv[KI + LC];
  for (int row = w; row < KI + LC; row += 4) {
    const float* src = (row < KI) ? imgs + (size_t)(i * KI + row) * DD
                                  : caps + (size_t)(t * LC + (row - KI)) * DD;
    float ss = 0.f;
    for (int e = lane; e < DD; e += 64) { float x = src[e] + EPSF; ss += x * x; }
    #pragma unroll
    for (int m = 32; m; m >>= 1) ss += __shfl_xor(ss, m);
    if (lane == 0) inv[row] = 1.0f / sqrtf(ss);
  }
  __syncthreads();
  const int il = ilen[i], cl = clen[t];
  float vals[8];
  #pragma unroll
  for (int r = 0; r < 8; ++r) {
    int p = tid + (r << 8);
    float v = 0.f;
    if (p < NEL) {
      int k = p / LC, l = p - k * LC;
      if (k < il && l < cl) {
        const float* ar = imgs + (size_t)(i * KI + k) * DD;
        const float* br = caps + (size_t)(t * LC + l) * DD;
        float s = 0.f;
        for (int dd = 0; dd < DD; dd += 4) {
          float4 a4 = *(const float4*)(ar + dd);
          float4 b4 = *(const float4*)(br + dd);
          s += (a4.x + EPSF) * (b4.x + EPSF) + (a4.y + EPSF) * (b4.y + EPSF)
             + (a4.z + EPSF) * (b4.z + EPSF) + (a4.w + EPSF) * (b4.w + EPSF);
        }
        v = s * inv[k] * inv[KI + l];
      }
    }
    vals[r] = v;
  }
  __shared__ float red[8];
  sparsemax_out(vals, tid, red, &out[b]);
}

extern "C" void kernel_launch(void* const* d_in, const int* in_sizes, int n_in,
                              void* d_out, int out_size, void* d_ws, size_t ws_size,
                              hipStream_t stream) {
  (void)in_sizes; (void)n_in; (void)out_size;
  const float* imgs = (const float*)d_in[1];
  const float* caps = (const float*)d_in[3];
  const int*   ilen = (const int*)d_in[4];
  const int*   clen = (const int*)d_in[5];
  float* out = (float*)d_out;

  const size_t offB     = (size_t)GM * DD * sizeof(u16);          //  9,437,184
  const size_t offC     = offB + (size_t)GN * DD * sizeof(u16);   // 22,544,384 (16B-aligned)
  const size_t needFull = offC + (size_t)GM * GN * sizeof(float); // 140,509,184
  u16*   A = (u16*)d_ws;
  u16*   B = (u16*)((char*)d_ws + offB);
  float* C = (float*)((char*)d_ws + offC);

  if (ws_size >= needFull) {
    hcam_normcast<<<dim3(GM + GN), dim3(256), 0, stream>>>(imgs, caps, A, B);
    hcam_gemm<<<dim3((GM / 128) * (GN / 128)), dim3(256), 0, stream>>>(A, B, C);
    hcam_spmax<<<dim3(NBI * NBT), dim3(256), 0, stream>>>(C, ilen, clen, out);
  } else if (ws_size >= offC) {
    hcam_normcast<<<dim3(GM + GN), dim3(256), 0, stream>>>(imgs, caps, A, B);
    hcam_fused_bf<<<dim3(NBI * NBT), dim3(256), 0, stream>>>(A, B, ilen, clen, out);
  } else {
    hcam_fused_raw<<<dim3(NBI * NBT), dim3(256), 0, stream>>>(imgs, caps, ilen, clen, out);
  }
}

// Round 2
// 174.167 us; speedup vs baseline: 1.1311x; 1.1311x over previous
//
#include <hip/hip_runtime.h>
#include <stdint.h>

#define EPSF 1e-6f

typedef unsigned short u16;
typedef __attribute__((ext_vector_type(8))) u16 u16x8;
typedef __attribute__((ext_vector_type(8))) __bf16 bf16x8;
typedef __attribute__((ext_vector_type(4))) float f32x4;

static constexpr int NBI = 128, NBT = 128, KI = 36, LC = 50, DD = 1024;
static constexpr int NEL = KI * LC;   // 1800
static constexpr int GM  = NBI * KI;  // 4608
static constexpr int GN  = NBT * LC;  // 6400
static constexpr int BM = 256, BN = 256, BK = 64;
static constexpr int KT  = DD / BK;   // 16 K-tiles
static constexpr int MT  = GM / BM;   // 18
static constexpr int NTT = GN / BN;   // 25
static constexpr int TB  = BM * BK;   // 16384 elems = 32KB per buf per matrix

static __device__ __forceinline__ u16 f2bf(float f) {  // RNE
  uint32_t u = __float_as_uint(f);
  u += 0x7fffu + ((u >> 16) & 1u);
  return (u16)(u >> 16);
}
static __device__ __forceinline__ float bf2f(u16 h) {
  return __uint_as_float((uint32_t)h << 16);
}

typedef __attribute__((address_space(1))) void gv_t;
typedef __attribute__((address_space(3))) void lv_t;
static __device__ __forceinline__ void gload16(const void* g, void* l) {
  __builtin_amdgcn_global_load_lds((const gv_t*)g, (lv_t*)l, 16, 0, 0);
}

// ---------------- kernel 0: add EPS, L2-normalize rows, cast to bf16 ----------------
__global__ __launch_bounds__(256) void hcam_normcast(
    const float* __restrict__ imgs, const float* __restrict__ caps,
    u16* __restrict__ A, u16* __restrict__ B) {
  int r = blockIdx.x;
  const float* src; u16* dst;
  if (r < GM) { src = imgs + (size_t)r * DD;        dst = A + (size_t)r * DD; }
  else        { src = caps + (size_t)(r - GM) * DD; dst = B + (size_t)(r - GM) * DD; }
  int tid = threadIdx.x;
  float4 v = *(const float4*)(src + tid * 4);
  v.x += EPSF; v.y += EPSF; v.z += EPSF; v.w += EPSF;
  float ss = v.x * v.x + v.y * v.y + v.z * v.z + v.w * v.w;
  #pragma unroll
  for (int m = 32; m; m >>= 1) ss += __shfl_xor(ss, m);
  __shared__ float wsum[4];
  if ((tid & 63) == 0) wsum[tid >> 6] = ss;
  __syncthreads();
  float inv = 1.0f / sqrtf(wsum[0] + wsum[1] + wsum[2] + wsum[3]);
  ushort4 o = make_ushort4(f2bf(v.x * inv), f2bf(v.y * inv), f2bf(v.z * inv), f2bf(v.w * inv));
  *(ushort4*)(dst + tid * 4) = o;
}

// ---------------- kernel 1: C = A * B^T, 256x256 tile, BK=64, 8-wave deep pipeline ----
// LDS: 2 bufs x (A 32KB + B 32KB) = 128KB. Swizzle: physical[row][c16] holds
// logical[row][c16 ^ (row&7)]; staged via inverse-swizzled GLOBAL source (linear
// gload_lds dest), read back with the same XOR (involution, rule #21).
// Schedule per K-tile t (buf cur=t&1): stages for t+1 spread as A0 (pre-barrier),
// B0/A1/B1 inside phases 0-2; ONE counted vmcnt(2) per tile boundary (tile t's 8
// loads are the oldest; only A0(t+1)'s 2 remain in flight). Barrier B2 = staged
// data visible to all waves; barrier B1 (end of tile) = all ds_reads of cur done
// before anyone stages t+2 into it.
__global__ __launch_bounds__(512, 2) void hcam_gemm8(
    const u16* __restrict__ A, const u16* __restrict__ B, float* __restrict__ C) {
  __shared__ u16 As[2 * TB];
  __shared__ u16 Bs[2 * TB];

  // bijective XCD swizzle (450 wgs, 450 % 8 != 0 -> m204 formula)
  const int nwg = MT * NTT;
  int orig = blockIdx.x;
  int qq = nwg >> 3, rr = nwg & 7;
  int xcd = orig & 7, idx = orig >> 3;
  int wg = (xcd < rr ? xcd * (qq + 1) : rr * (qq + 1) + (xcd - rr) * qq) + idx;
  const int bm = wg % MT, bn = wg / MT;

  const int tid = threadIdx.x, lane = tid & 63, w = tid >> 6;
  const int wm = w >> 2, wn = w & 3;          // 2(M) x 4(N) waves, 128x64 out each
  const u16* Ag = A + (size_t)(bm * BM) * DD;
  const u16* Bg = B + (size_t)(bn * BN) * DD;

  const int srow = tid >> 3;                  // staging row within 64-row group
  const int sc16 = (tid & 7) ^ (srow & 7);    // inverse-swizzled logical col16
  const int wbase = w * 8;                    // wave-uniform LDS row base

  // issue one half-tile (128 rows x 64 k) = 2 x gload16/thread
  auto stage = [&](const u16* g, u16* lds, int kt, int h) {
    #pragma unroll
    for (int j = 0; j < 2; ++j) {
      int row = h * 128 + j * 64 + srow;
      gload16(g + (size_t)row * DD + kt * BK + sc16 * 8,
              lds + (h * 128 + j * 64 + wbase) * BK);
    }
  };

  f32x4 acc[8][4];
  #pragma unroll
  for (int i = 0; i < 8; ++i)
    #pragma unroll
    for (int j = 0; j < 4; ++j) acc[i][j] = (f32x4){0.f, 0.f, 0.f, 0.f};

  const int fr = lane & 15, g4 = lane >> 4;   // frag row + col16 group

  auto tile = [&](int t, u16* as_c, u16* bs_c, u16* as_n, u16* bs_n) {
    const int tn = t + 1;
    if (tn < KT) {
      stage(Ag, as_n, tn, 0);                              // A0(t+1)
      asm volatile("s_waitcnt vmcnt(2)" ::: "memory");     // tile t fully landed
    } else {
      asm volatile("s_waitcnt vmcnt(0)" ::: "memory");
    }
    __builtin_amdgcn_s_barrier();                          // B2
    __builtin_amdgcn_sched_barrier(0);
    #pragma unroll
    for (int ph = 0; ph < 4; ++ph) {
      const int mh = (ph == 0 || ph == 3) ? 0 : 1;         // Q00,Q10,Q11,Q01
      const int nh = (ph >= 2) ? 1 : 0;
      bf16x8 af[2][4], bfv[2][2];
      #pragma unroll
      for (int k2 = 0; k2 < 2; ++k2) {
        const int c16 = k2 * 4 + g4;
        const int cs = (c16 ^ (fr & 7)) << 3;              // swizzled read col
        #pragma unroll
        for (int mi = 0; mi < 4; ++mi) {
          int rowl = wm * 128 + mh * 64 + mi * 16 + fr;
          af[k2][mi] = __builtin_bit_cast(bf16x8, *(const u16x8*)(as_c + rowl * BK + cs));
        }
        #pragma unroll
        for (int ni = 0; ni < 2; ++ni) {
          int rowl = wn * 64 + nh * 32 + ni * 16 + fr;
          bfv[k2][ni] = __builtin_bit_cast(bf16x8, *(const u16x8*)(bs_c + rowl * BK + cs));
        }
      }
      if (tn < KT) {                                       // B0,A1,B1 of t+1
        if (ph == 0)      stage(Bg, bs_n, tn, 0);
        else if (ph == 1) stage(Ag, as_n, tn, 1);
        else if (ph == 2) stage(Bg, bs_n, tn, 1);
      }
      __builtin_amdgcn_s_setprio(1);
      #pragma unroll
      for (int k2 = 0; k2 < 2; ++k2)
        #pragma unroll
        for (int mi = 0; mi < 4; ++mi)
          #pragma unroll
          for (int ni = 0; ni < 2; ++ni)
            acc[mh * 4 + mi][nh * 2 + ni] = __builtin_amdgcn_mfma_f32_16x16x32_bf16(
                af[k2][mi], bfv[k2][ni], acc[mh * 4 + mi][nh * 2 + ni], 0, 0, 0);
      __builtin_amdgcn_s_setprio(0);
    }
    __builtin_amdgcn_s_barrier();                          // B1: cur reads done
    __builtin_amdgcn_sched_barrier(0);
  };

  // prologue: tile 0 -> buf 0 (8 loads/thread)
  stage(Ag, As, 0, 0); stage(Ag, As, 0, 1);
  stage(Bg, Bs, 0, 0); stage(Bg, Bs, 0, 1);

  #pragma unroll 1
  for (int tp = 0; tp < KT; tp += 2) {
    tile(tp,     As,      Bs,      As + TB, Bs + TB);
    tile(tp + 1, As + TB, Bs + TB, As,      Bs);
  }

  // C/D layout: col = lane&15, row = (lane>>4)*4 + j (m89-verified)
  const int fc = lane & 15, fq = (lane >> 4) * 4;
  #pragma unroll
  for (int am = 0; am < 8; ++am) {
    #pragma unroll
    for (int an = 0; an < 4; ++an) {
      const int row0 = bm * BM + wm * 128 + am * 16 + fq;
      const int col  = bn * BN + wn * 64 + an * 16 + fc;
      #pragma unroll
      for (int j = 0; j < 4; ++j)
        C[(size_t)(row0 + j) * GN + col] = acc[am][an][j];
    }
  }
}

// ---------------- block reduction of two floats (256 threads) ----------------
static __device__ __forceinline__ void bred2(float& a, float& b2, int tid, float* red) {
  #pragma unroll
  for (int m = 32; m; m >>= 1) { a += __shfl_xor(a, m); b2 += __shfl_xor(b2, m); }
  __syncthreads();
  if ((tid & 63) == 0) { red[(tid >> 6) * 2] = a; red[(tid >> 6) * 2 + 1] = b2; }
  __syncthreads();
  a  = red[0] + red[2] + red[4] + red[6];
  b2 = red[1] + red[3] + red[5] + red[7];
}

// ---------------- sparsemax over 1800 register-resident values + weighted sum -------
static __device__ __forceinline__ void sparsemax_out(float vals[8], int tid, float* red, float* outp) {
  float s = 0.f, d = 0.f;
  #pragma unroll
  for (int r = 0; r < 8; ++r) { int p = tid + (r << 8); if (p < NEL) s += vals[r]; }
  bred2(s, d, tid, red);
  float tau  = (s - 1.0f) * (1.0f / NEL);
  float prev = (float)NEL;
  for (int it = 0; it < 64; ++it) {
    float ss = 0.f, cc = 0.f;
    #pragma unroll
    for (int r = 0; r < 8; ++r) {
      int p = tid + (r << 8);
      if (p < NEL && vals[r] > tau) { ss += vals[r]; cc += 1.0f; }
    }
    bred2(ss, cc, tid, red);
    if (cc == prev || cc < 1.0f) break;
    float tn = (ss - 1.0f) / cc;
    prev = cc;
    if (tn <= tau) break;
    tau = tn;
  }
  float o = 0.f; d = 0.f;
  #pragma unroll
  for (int r = 0; r < 8; ++r) {
    float v = vals[r], a2 = v - tau;
    if (a2 > 0.f) o += v * a2;
  }
  bred2(o, d, tid, red);
  if (tid == 0) *outp = o;
}

// ---------------- kernel 2: gather fg block, mask, sparsemax, output ----------------
__global__ __launch_bounds__(256) void hcam_spmax(
    const float* __restrict__ C, const int* __restrict__ ilen, const int* __restrict__ clen,
    float* __restrict__ out) {
  const int b = blockIdx.x;
  const int i = b >> 7, t = b & 127;
  const int tid = threadIdx.x;
  const int il = ilen[i], cl = clen[t];
  const float* base = C + (size_t)i * KI * GN + t * LC;
  float vals[8];
  #pragma unroll
  for (int r = 0; r < 8; ++r) {
    int p = tid + (r << 8);
    float v = 0.f;
    if (p < NEL) {
      int k = p / LC, l = p - k * LC;
      if (k < il && l < cl) v = base[(size_t)k * GN + l];
    }
    vals[r] = v;
  }
  __shared__ float red[8];
  sparsemax_out(vals, tid, red, &out[b]);
}

// ---------------- fallback tier 2: fused dots from normalized bf16 ----------------
__global__ __launch_bounds__(256) void hcam_fused_bf(
    const u16* __restrict__ A, const u16* __restrict__ B,
    const int* __restrict__ ilen, const int* __restrict__ clen, float* __restrict__ out) {
  const int b = blockIdx.x;
  const int i = b >> 7, t = b & 127;
  const int tid = threadIdx.x;
  const int il = ilen[i], cl = clen[t];
  float vals[8];
  #pragma unroll
  for (int r = 0; r < 8; ++r) {
    int p = tid + (r << 8);
    float v = 0.f;
    if (p < NEL) {
      int k = p / LC, l = p - k * LC;
      if (k < il && l < cl) {
        const u16* ar = A + (size_t)(i * KI + k) * DD;
        const u16* br = B + (size_t)(t * LC + l) * DD;
        float s = 0.f;
        for (int dd = 0; dd < DD; dd += 8) {
          u16x8 av = *(const u16x8*)(ar + dd);
          u16x8 bv = *(const u16x8*)(br + dd);
          #pragma unroll
          for (int q = 0; q < 8; ++q) s += bf2f(av[q]) * bf2f(bv[q]);
        }
        v = s;
      }
    }
    vals[r] = v;
  }
  __shared__ float red[8];
  sparsemax_out(vals, tid, red, &out[b]);
}

// ---------------- fallback tier 3: fully fused, norms recomputed ----------------
__global__ __launch_bounds__(256) void hcam_fused_raw(
    const float* __restrict__ imgs, const float* __restrict__ caps,
    const int* __restrict__ ilen, const int* __restrict__ clen, float* __restrict__ out) {
  const int b = blockIdx.x;
  const int i = b >> 7, t = b & 127;
  const int tid = threadIdx.x;
  const int w = tid >> 6, lane = tid & 63;
  __shared__ float inv[KI + LC];
  for (int row = w; row < KI + LC; row += 4) {
    const float* src = (row < KI) ? imgs + (size_t)(i * KI + row) * DD
                                  : caps + (size_t)(t * LC + (row - KI)) * DD;
    float ss = 0.f;
    for (int e = lane; e < DD; e += 64) { float x = src[e] + EPSF; ss += x * x; }
    #pragma unroll
    for (int m = 32; m; m >>= 1) ss += __shfl_xor(ss, m);
    if (lane == 0) inv[row] = 1.0f / sqrtf(ss);
  }
  __syncthreads();
  const int il = ilen[i], cl = clen[t];
  float vals[8];
  #pragma unroll
  for (int r = 0; r < 8; ++r) {
    int p = tid + (r << 8);
    float v = 0.f;
    if (p < NEL) {
      int k = p / LC, l = p - k * LC;
      if (k < il && l < cl) {
        const float* ar = imgs + (size_t)(i * KI + k) * DD;
        const float* br = caps + (size_t)(t * LC + l) * DD;
        float s = 0.f;
        for (int dd = 0; dd < DD; dd += 4) {
          float4 a4 = *(const float4*)(ar + dd);
          float4 b4 = *(const float4*)(br + dd);
          s += (a4.x + EPSF) * (b4.x + EPSF) + (a4.y + EPSF) * (b4.y + EPSF)
             + (a4.z + EPSF) * (b4.z + EPSF) + (a4.w + EPSF) * (b4.w + EPSF);
        }
        v = s * inv[k] * inv[KI + l];
      }
    }
    vals[r] = v;
  }
  __shared__ float red[8];
  sparsemax_out(vals, tid, red, &out[b]);
}

extern "C" void kernel_launch(void* const* d_in, const int* in_sizes, int n_in,
                              void* d_out, int out_size, void* d_ws, size_t ws_size,
                              hipStream_t stream) {
  (void)in_sizes; (void)n_in; (void)out_size;
  const float* imgs = (const float*)d_in[1];
  const float* caps = (const float*)d_in[3];
  const int*   ilen = (const int*)d_in[4];
  const int*   clen = (const int*)d_in[5];
  float* out = (float*)d_out;

  const size_t offB     = (size_t)GM * DD * sizeof(u16);
  const size_t offC     = offB + (size_t)GN * DD * sizeof(u16);
  const size_t needFull = offC + (size_t)GM * GN * sizeof(float);
  u16*   A = (u16*)d_ws;
  u16*   B = (u16*)((char*)d_ws + offB);
  float* C = (float*)((char*)d_ws + offC);

  if (ws_size >= needFull) {
    hcam_normcast<<<dim3(GM + GN), dim3(256), 0, stream>>>(imgs, caps, A, B);
    hcam_gemm8<<<dim3(MT * NTT), dim3(512), 0, stream>>>(A, B, C);
    hcam_spmax<<<dim3(NBI * NBT), dim3(256), 0, stream>>>(C, ilen, clen, out);
  } else if (ws_size >= offC) {
    hcam_normcast<<<dim3(GM + GN), dim3(256), 0, stream>>>(imgs, caps, A, B);
    hcam_fused_bf<<<dim3(NBI * NBT), dim3(256), 0, stream>>>(A, B, ilen, clen, out);
  } else {
    hcam_fused_raw<<<dim3(NBI * NBT), dim3(256), 0, stream>>>(imgs, caps, ilen, clen, out);
  }
}

// Round 3
// 132.237 us; speedup vs baseline: 1.4897x; 1.3171x over previous
//
#include <hip/hip_runtime.h>
#include <stdint.h>

#define EPSF 1e-6f

typedef unsigned short u16;
typedef __attribute__((ext_vector_type(8))) u16 u16x8;
typedef __attribute__((ext_vector_type(8))) __bf16 bf16x8;
typedef __attribute__((ext_vector_type(4))) float f32x4;

static constexpr int NBI = 128, NBT = 128, KI = 36, LC = 50, DD = 1024;
static constexpr int NEL = KI * LC;   // 1800
static constexpr int GM  = NBI * KI;  // 4608
static constexpr int GN  = NBT * LC;  // 6400
static constexpr int BM = 256, BN = 256, BK = 64;
static constexpr int KT  = DD / BK;   // 16
static constexpr int MT  = GM / BM;   // 18
static constexpr int NTT = GN / BN;   // 25
static constexpr int TB  = BM * BK;   // 16384 elems

static __device__ __forceinline__ u16 f2bf(float f) {  // RNE
  uint32_t u = __float_as_uint(f);
  u += 0x7fffu + ((u >> 16) & 1u);
  return (u16)(u >> 16);
}
static __device__ __forceinline__ float bf2f(u16 h) {
  return __uint_as_float((uint32_t)h << 16);
}

typedef __attribute__((address_space(1))) void gv_t;
typedef __attribute__((address_space(3))) void lv_t;
static __device__ __forceinline__ void gload16(const void* g, void* l) {
  __builtin_amdgcn_global_load_lds((const gv_t*)g, (lv_t*)l, 16, 0, 0);
}

// ---------------- kernel 0: add EPS, L2-normalize rows, cast to bf16 ----------------
__global__ __launch_bounds__(256) void hcam_normcast(
    const float* __restrict__ imgs, const float* __restrict__ caps,
    u16* __restrict__ A, u16* __restrict__ B) {
  int r = blockIdx.x;
  const float* src; u16* dst;
  if (r < GM) { src = imgs + (size_t)r * DD;        dst = A + (size_t)r * DD; }
  else        { src = caps + (size_t)(r - GM) * DD; dst = B + (size_t)(r - GM) * DD; }
  int tid = threadIdx.x;
  float4 v = *(const float4*)(src + tid * 4);
  v.x += EPSF; v.y += EPSF; v.z += EPSF; v.w += EPSF;
  float ss = v.x * v.x + v.y * v.y + v.z * v.z + v.w * v.w;
  #pragma unroll
  for (int m = 32; m; m >>= 1) ss += __shfl_xor(ss, m);
  __shared__ float wsum[4];
  if ((tid & 63) == 0) wsum[tid >> 6] = ss;
  __syncthreads();
  float inv = 1.0f / sqrtf(wsum[0] + wsum[1] + wsum[2] + wsum[3]);
  ushort4 o = make_ushort4(f2bf(v.x * inv), f2bf(v.y * inv), f2bf(v.z * inv), f2bf(v.w * inv));
  *(ushort4*)(dst + tid * 4) = o;
}

// ---------------- kernel 1: C = A * B^T, 256x256 tile, BK=64, 8-wave deep pipeline ----
__global__ __launch_bounds__(512, 2) void hcam_gemm8(
    const u16* __restrict__ A, const u16* __restrict__ B, float* __restrict__ C) {
  __shared__ u16 As[2 * TB];
  __shared__ u16 Bs[2 * TB];

  const int nwg = MT * NTT;
  int orig = blockIdx.x;
  int qq = nwg >> 3, rr = nwg & 7;
  int xcd = orig & 7, idx = orig >> 3;
  int wg = (xcd < rr ? xcd * (qq + 1) : rr * (qq + 1) + (xcd - rr) * qq) + idx;
  const int bm = wg % MT, bn = wg / MT;

  const int tid = threadIdx.x, lane = tid & 63, w = tid >> 6;
  const int wm = w >> 2, wn = w & 3;
  const u16* Ag = A + (size_t)(bm * BM) * DD;
  const u16* Bg = B + (size_t)(bn * BN) * DD;

  const int srow = tid >> 3;
  const int sc16 = (tid & 7) ^ (srow & 7);
  const int wbase = w * 8;

  auto stage = [&](const u16* g, u16* lds, int kt, int h) {
    #pragma unroll
    for (int j = 0; j < 2; ++j) {
      int row = h * 128 + j * 64 + srow;
      gload16(g + (size_t)row * DD + kt * BK + sc16 * 8,
              lds + (h * 128 + j * 64 + wbase) * BK);
    }
  };

  f32x4 acc[8][4];
  #pragma unroll
  for (int i = 0; i < 8; ++i)
    #pragma unroll
    for (int j = 0; j < 4; ++j) acc[i][j] = (f32x4){0.f, 0.f, 0.f, 0.f};

  const int fr = lane & 15, g4 = lane >> 4;

  auto tile = [&](int t, u16* as_c, u16* bs_c, u16* as_n, u16* bs_n) {
    const int tn = t + 1;
    if (tn < KT) {
      stage(Ag, as_n, tn, 0);
      asm volatile("s_waitcnt vmcnt(2)" ::: "memory");
    } else {
      asm volatile("s_waitcnt vmcnt(0)" ::: "memory");
    }
    __builtin_amdgcn_s_barrier();
    __builtin_amdgcn_sched_barrier(0);
    #pragma unroll
    for (int ph = 0; ph < 4; ++ph) {
      const int mh = (ph == 0 || ph == 3) ? 0 : 1;
      const int nh = (ph >= 2) ? 1 : 0;
      bf16x8 af[2][4], bfv[2][2];
      #pragma unroll
      for (int k2 = 0; k2 < 2; ++k2) {
        const int c16 = k2 * 4 + g4;
        const int cs = (c16 ^ (fr & 7)) << 3;
        #pragma unroll
        for (int mi = 0; mi < 4; ++mi) {
          int rowl = wm * 128 + mh * 64 + mi * 16 + fr;
          af[k2][mi] = __builtin_bit_cast(bf16x8, *(const u16x8*)(as_c + rowl * BK + cs));
        }
        #pragma unroll
        for (int ni = 0; ni < 2; ++ni) {
          int rowl = wn * 64 + nh * 32 + ni * 16 + fr;
          bfv[k2][ni] = __builtin_bit_cast(bf16x8, *(const u16x8*)(bs_c + rowl * BK + cs));
        }
      }
      if (tn < KT) {
        if (ph == 0)      stage(Bg, bs_n, tn, 0);
        else if (ph == 1) stage(Ag, as_n, tn, 1);
        else if (ph == 2) stage(Bg, bs_n, tn, 1);
      }
      __builtin_amdgcn_s_setprio(1);
      #pragma unroll
      for (int k2 = 0; k2 < 2; ++k2)
        #pragma unroll
        for (int mi = 0; mi < 4; ++mi)
          #pragma unroll
          for (int ni = 0; ni < 2; ++ni)
            acc[mh * 4 + mi][nh * 2 + ni] = __builtin_amdgcn_mfma_f32_16x16x32_bf16(
                af[k2][mi], bfv[k2][ni], acc[mh * 4 + mi][nh * 2 + ni], 0, 0, 0);
      __builtin_amdgcn_s_setprio(0);
    }
    __builtin_amdgcn_s_barrier();
    __builtin_amdgcn_sched_barrier(0);
  };

  stage(Ag, As, 0, 0); stage(Ag, As, 0, 1);
  stage(Bg, Bs, 0, 0); stage(Bg, Bs, 0, 1);

  #pragma unroll 1
  for (int tp = 0; tp < KT; tp += 2) {
    tile(tp,     As,      Bs,      As + TB, Bs + TB);
    tile(tp + 1, As + TB, Bs + TB, As,      Bs);
  }

  const int fc = lane & 15, fq = (lane >> 4) * 4;
  #pragma unroll
  for (int am = 0; am < 8; ++am) {
    #pragma unroll
    for (int an = 0; an < 4; ++an) {
      const int row0 = bm * BM + wm * 128 + am * 16 + fq;
      const int col  = bn * BN + wn * 64 + an * 16 + fc;
      #pragma unroll
      for (int j = 0; j < 4; ++j)
        C[(size_t)(row0 + j) * GN + col] = acc[am][an][j];
    }
  }
}

// ---------------- kernel 2: wave-per-row sparsemax + weighted sum ----------------
// One 64-lane wave owns one (i,t) row. 1800 values in 29 regs/lane (p = lane + 64r).
// Masked/pad slots = -1e30 (self-excluding). The m = 1800 - il*cl exact zeros of the
// reference participate analytically: they join the support count only while tau < 0,
// contribute 0 to sums and 0 to the output. Michelot: tau <- (sum_{z>tau}-1)/cnt,
// monotone increasing from the full-set start -> converges to exact tau*.
static constexpr int RPT = (NEL + 63) / 64;   // 29

__global__ __launch_bounds__(256) void hcam_spmax_w(
    const float* __restrict__ C, const int* __restrict__ ilen, const int* __restrict__ clen,
    float* __restrict__ out) {
  const int wid  = blockIdx.x * 4 + (threadIdx.x >> 6);
  const int lane = threadIdx.x & 63;
  const int i = wid >> 7, t = wid & 127;
  const int il = ilen[i], cl = clen[t];
  const float* base = C + (size_t)i * KI * GN + t * LC;

  float v[RPT];
  float sum = 0.f;
  #pragma unroll
  for (int r = 0; r < RPT; ++r) {
    int p = lane + (r << 6);
    float x = -1e30f;
    if (p < NEL) {
      int k = p / LC, l = p - k * LC;
      if (k < il && l < cl) { x = base[(size_t)k * GN + l]; sum += x; }
    }
    v[r] = x;
  }
  #pragma unroll
  for (int m = 32; m; m >>= 1) sum += __shfl_xor(sum, m);

  const float mzero = (float)(NEL - il * cl);
  float tau  = (sum - 1.0f) * (1.0f / NEL);   // full-set Michelot start (zeros included)
  float prev = (float)NEL;
  for (int it = 0; it < 32; ++it) {
    float ss = 0.f, cc = 0.f;
    #pragma unroll
    for (int r = 0; r < RPT; ++r) {
      if (v[r] > tau) { ss += v[r]; cc += 1.0f; }
    }
    #pragma unroll
    for (int m = 32; m; m >>= 1) { ss += __shfl_xor(ss, m); cc += __shfl_xor(cc, m); }
    if (tau < 0.f) cc += mzero;               // the m zeros are still in support
    if (cc == prev || cc < 1.0f) break;       // support stable -> tau exact
    float tn = (ss - 1.0f) / cc;
    prev = cc;
    if (tn <= tau) break;                     // fp rounding guard (tau must increase)
    tau = tn;
  }

  float o = 0.f;
  #pragma unroll
  for (int r = 0; r < RPT; ++r) {
    float d = v[r] - tau;
    if (d > 0.f) o += v[r] * d;               // zeros contribute 0 either way
  }
  #pragma unroll
  for (int m = 32; m; m >>= 1) o += __shfl_xor(o, m);
  if (lane == 0) out[wid] = o;
}

// ---------------- block reduction of two floats (fallback path) ----------------
static __device__ __forceinline__ void bred2(float& a, float& b2, int tid, float* red) {
  #pragma unroll
  for (int m = 32; m; m >>= 1) { a += __shfl_xor(a, m); b2 += __shfl_xor(b2, m); }
  __syncthreads();
  if ((tid & 63) == 0) { red[(tid >> 6) * 2] = a; red[(tid >> 6) * 2 + 1] = b2; }
  __syncthreads();
  a  = red[0] + red[2] + red[4] + red[6];
  b2 = red[1] + red[3] + red[5] + red[7];
}

static __device__ __forceinline__ void sparsemax_out(float vals[8], int tid, float* red, float* outp) {
  float s = 0.f, d = 0.f;
  #pragma unroll
  for (int r = 0; r < 8; ++r) { int p = tid + (r << 8); if (p < NEL) s += vals[r]; }
  bred2(s, d, tid, red);
  float tau  = (s - 1.0f) * (1.0f / NEL);
  float prev = (float)NEL;
  for (int it = 0; it < 64; ++it) {
    float ss = 0.f, cc = 0.f;
    #pragma unroll
    for (int r = 0; r < 8; ++r) {
      int p = tid + (r << 8);
      if (p < NEL && vals[r] > tau) { ss += vals[r]; cc += 1.0f; }
    }
    bred2(ss, cc, tid, red);
    if (cc == prev || cc < 1.0f) break;
    float tn = (ss - 1.0f) / cc;
    prev = cc;
    if (tn <= tau) break;
    tau = tn;
  }
  float o = 0.f; d = 0.f;
  #pragma unroll
  for (int r = 0; r < 8; ++r) {
    float v = vals[r], a2 = v - tau;
    if (a2 > 0.f) o += v * a2;
  }
  bred2(o, d, tid, red);
  if (tid == 0) *outp = o;
}

// ---------------- fallback tier 2: fused dots from normalized bf16 ----------------
__global__ __launch_bounds__(256) void hcam_fused_bf(
    const u16* __restrict__ A, const u16* __restrict__ B,
    const int* __restrict__ ilen, const int* __restrict__ clen, float* __restrict__ out) {
  const int b = blockIdx.x;
  const int i = b >> 7, t = b & 127;
  const int tid = threadIdx.x;
  const int il = ilen[i], cl = clen[t];
  float vals[8];
  #pragma unroll
  for (int r = 0; r < 8; ++r) {
    int p = tid + (r << 8);
    float v = 0.f;
    if (p < NEL) {
      int k = p / LC, l = p - k * LC;
      if (k < il && l < cl) {
        const u16* ar = A + (size_t)(i * KI + k) * DD;
        const u16* br = B + (size_t)(t * LC + l) * DD;
        float s = 0.f;
        for (int dd = 0; dd < DD; dd += 8) {
          u16x8 av = *(const u16x8*)(ar + dd);
          u16x8 bv = *(const u16x8*)(br + dd);
          #pragma unroll
          for (int q = 0; q < 8; ++q) s += bf2f(av[q]) * bf2f(bv[q]);
        }
        v = s;
      }
    }
    vals[r] = v;
  }
  __shared__ float red[8];
  sparsemax_out(vals, tid, red, &out[b]);
}

// ---------------- fallback tier 3: fully fused, norms recomputed ----------------
__global__ __launch_bounds__(256) void hcam_fused_raw(
    const float* __restrict__ imgs, const float* __restrict__ caps,
    const int* __restrict__ ilen, const int* __restrict__ clen, float* __restrict__ out) {
  const int b = blockIdx.x;
  const int i = b >> 7, t = b & 127;
  const int tid = threadIdx.x;
  const int w = tid >> 6, lane = tid & 63;
  __shared__ float inv[KI + LC];
  for (int row = w; row < KI + LC; row += 4) {
    const float* src = (row < KI) ? imgs + (size_t)(i * KI + row) * DD
                                  : caps + (size_t)(t * LC + (row - KI)) * DD;
    float ss = 0.f;
    for (int e = lane; e < DD; e += 64) { float x = src[e] + EPSF; ss += x * x; }
    #pragma unroll
    for (int m = 32; m; m >>= 1) ss += __shfl_xor(ss, m);
    if (lane == 0) inv[row] = 1.0f / sqrtf(ss);
  }
  __syncthreads();
  const int il = ilen[i], cl = clen[t];
  float vals[8];
  #pragma unroll
  for (int r = 0; r < 8; ++r) {
    int p = tid + (r << 8);
    float v = 0.f;
    if (p < NEL) {
      int k = p / LC, l = p - k * LC;
      if (k < il && l < cl) {
        const float* ar = imgs + (size_t)(i * KI + k) * DD;
        const float* br = caps + (size_t)(t * LC + l) * DD;
        float s = 0.f;
        for (int dd = 0; dd < DD; dd += 4) {
          float4 a4 = *(const float4*)(ar + dd);
          float4 b4 = *(const float4*)(br + dd);
          s += (a4.x + EPSF) * (b4.x + EPSF) + (a4.y + EPSF) * (b4.y + EPSF)
             + (a4.z + EPSF) * (b4.z + EPSF) + (a4.w + EPSF) * (b4.w + EPSF);
        }
        v = s * inv[k] * inv[KI + l];
      }
    }
    vals[r] = v;
  }
  __shared__ float red[8];
  sparsemax_out(vals, tid, red, &out[b]);
}

extern "C" void kernel_launch(void* const* d_in, const int* in_sizes, int n_in,
                              void* d_out, int out_size, void* d_ws, size_t ws_size,
                              hipStream_t stream) {
  (void)in_sizes; (void)n_in; (void)out_size;
  const float* imgs = (const float*)d_in[1];
  const float* caps = (const float*)d_in[3];
  const int*   ilen = (const int*)d_in[4];
  const int*   clen = (const int*)d_in[5];
  float* out = (float*)d_out;

  const size_t offB     = (size_t)GM * DD * sizeof(u16);
  const size_t offC     = offB + (size_t)GN * DD * sizeof(u16);
  const size_t needFull = offC + (size_t)GM * GN * sizeof(float);
  u16*   A = (u16*)d_ws;
  u16*   B = (u16*)((char*)d_ws + offB);
  float* C = (float*)((char*)d_ws + offC);

  if (ws_size >= needFull) {
    hcam_normcast<<<dim3(GM + GN), dim3(256), 0, stream>>>(imgs, caps, A, B);
    hcam_gemm8<<<dim3(MT * NTT), dim3(512), 0, stream>>>(A, B, C);
    hcam_spmax_w<<<dim3(NBI * NBT / 4), dim3(256), 0, stream>>>(C, ilen, clen, out);
  } else if (ws_size >= offC) {
    hcam_normcast<<<dim3(GM + GN), dim3(256), 0, stream>>>(imgs, caps, A, B);
    hcam_fused_bf<<<dim3(NBI * NBT), dim3(256), 0, stream>>>(A, B, ilen, clen, out);
  } else {
    hcam_fused_raw<<<dim3(NBI * NBT), dim3(256), 0, stream>>>(imgs, caps, ilen, clen, out);
  }
}